// Round 12
// baseline (299.442 us; speedup 1.0000x reference)
//
#include <hip/hip_runtime.h>
#include <hip/hip_bf16.h>
#include <stdint.h>

#define T_SEQ 4096
#define C_DIM 2048
#define H_DIM 128
#define NBATCH 4

typedef unsigned short u16;
typedef __attribute__((ext_vector_type(8))) __bf16 bf16x8;
typedef __attribute__((ext_vector_type(4))) float f32x4;
typedef __attribute__((ext_vector_type(8))) unsigned short u16x8;
typedef __attribute__((ext_vector_type(4))) unsigned short u16x4;

__device__ __forceinline__ u16 f2bf(float f) {
  union { float f; uint32_t i; } v; v.f = f;
  uint32_t r = v.i + 0x7FFFu + ((v.i >> 16) & 1u);
  return (u16)(r >> 16);
}
__device__ __forceinline__ float bf2f(u16 u) {
  union { uint32_t i; float f; } v; v.i = ((uint32_t)u) << 16;
  return v.f;
}

__device__ __forceinline__ void gload16(const void* g, void* l) {
  __builtin_amdgcn_global_load_lds(
      (__attribute__((address_space(1))) void*)(g),
      (__attribute__((address_space(3))) void*)(l), 16, 0, 0);
}

__device__ __forceinline__ f32x4 mfma_bf16(bf16x8 a, bf16x8 b, f32x4 c) {
  return __builtin_amdgcn_mfma_f32_16x16x32_bf16(a, b, c, 0, 0, 0);
}

// DPP row rotate (16-lane row) reductions — no LDS traffic.
template<int CTRL>
__device__ __forceinline__ float dpp_mov(float x) {
  return __int_as_float(__builtin_amdgcn_mov_dpp(__float_as_int(x), CTRL, 0xF, 0xF, true));
}
__device__ __forceinline__ float red16_max(float v) {
  v = fmaxf(v, dpp_mov<0x121>(v));
  v = fmaxf(v, dpp_mov<0x122>(v));
  v = fmaxf(v, dpp_mov<0x124>(v));
  v = fmaxf(v, dpp_mov<0x128>(v));
  return v;
}
__device__ __forceinline__ float red16_sum(float v) {
  v += dpp_mov<0x121>(v);
  v += dpp_mov<0x122>(v);
  v += dpp_mov<0x124>(v);
  v += dpp_mov<0x128>(v);
  return v;
}

// ---------------------------------------------------------------------------
// Kernel 1: W fp32 [2048][128] -> Wt bf16 [p][n][k], pre-swizzled so that
// contiguous global_load_lds staging lands an XOR-swizzled B-tile in LDS.
// (unchanged, session-verified)
// ---------------------------------------------------------------------------
__global__ __launch_bounds__(256) void transpose_w(
    const float* __restrict__ Wq, const float* __restrict__ Wk,
    const float* __restrict__ Wv, u16* __restrict__ Wt)
{
  __shared__ u16 Wl[64 * 72];
  const int bk = blockIdx.x;   // k-tile 0..31
  const int bn = blockIdx.y;   // n-tile 0..1
  const int p  = blockIdx.z;   // 0 q, 1 k, 2 v
  const float* W = (p == 0) ? Wq : (p == 1) ? Wk : Wv;
  const int t = threadIdx.x;

  for (int ps = 0; ps < 16; ++ps) {
    int e  = ps * 256 + t;
    int kk = e >> 6, nn = e & 63;
    Wl[kk * 72 + nn] = f2bf(W[(size_t)(bk * 64 + kk) * H_DIM + bn * 64 + nn]);
  }
  __syncthreads();
  for (int ps = 0; ps < 16; ++ps) {
    int o  = ps * 256 + t;
    int nl = o >> 6, kl = o & 63;
    int n  = bn * 64 + nl;
    int g  = kl >> 3, j = kl & 7;
    int ks = ((g ^ (n & 7)) << 3) | j;
    Wt[(size_t)p * (H_DIM * C_DIM) + (size_t)n * C_DIM + bk * 64 + kl] = Wl[ks * 72 + nl];
  }
}

// ---------------------------------------------------------------------------
// Kernel 2: QKV GEMM, SPLIT BY OUTPUT (q/k/v one per block). R11 counters:
// qkv 87us with MfmaUtil 11%, Occ 21.8% -> one 512-thr block per CU (112 KB
// LDS), 8 waves locked to one barrier schedule, vmcnt(0)-drain x32 exposed.
// Fix mirrors the R7-flash lesson: independent blocks per CU. Grid (256,3),
// 256 thr (4 waves, wave tile 32x64), B-panel 16 KB, LDS 48 KB -> 3
// blocks/CU. x re-read 3x is L3-resident (134 MB < 256 MB, p-major
// dispatch). All swizzles/epilogues/QSCALE byte-identical per output.
// ---------------------------------------------------------------------------
__global__ __launch_bounds__(256, 3) void qkv_fused(
    const float* __restrict__ x, const u16* __restrict__ Wt,
    const float* __restrict__ bq, const float* __restrict__ bk, const float* __restrict__ bv,
    u16* __restrict__ qo, u16* __restrict__ ko, u16* __restrict__ vTo)
{
  __shared__ alignas(16) u16 SMEM[2][12288];   // 2 x (As 8KB | Bs 16KB) = 48 KB

  const int tid  = threadIdx.x;
  const int w    = tid >> 6, lane = tid & 63;
  const int t16  = lane & 15, quad = lane >> 4;
  const int mh   = w >> 1;        // m-half: rows mh*32..+32
  const int nq   = w & 1;         // n-strip: cols nq*64..+64
  const int rt   = blockIdx.x;    // 0..255 row tiles (64 rows each)
  const int p    = blockIdx.y;    // 0 q, 1 k, 2 v

  const u16* Wp = Wt + (size_t)p * (H_DIM * C_DIM);
  const float* bias_p = (p == 0) ? bq : (p == 1) ? bk : bv;

  f32x4 acc[2][4];
  for (int i = 0; i < 2; ++i)
    for (int j = 0; j < 4; ++j) acc[i][j] = f32x4{0.f, 0.f, 0.f, 0.f};

  const size_t rowBase = (size_t)rt * 64;
  const int arow = tid >> 3;      // 0..31 (this thread also does arow+32)
  const int ag   = tid & 7;       // 8-float granule
  const float* xr0 = &x[(rowBase + arow) * C_DIM + ag * 8];
  const float* xr1 = &x[(rowBase + arow + 32) * C_DIM + ag * 8];
  const int aswz = ((ag ^ (arow & 7)) << 3);   // (arow+32)&7 == arow&7

  float4 a0 = ((const float4*)xr0)[0];
  float4 a1 = ((const float4*)xr0)[1];
  float4 a2 = ((const float4*)xr1)[0];
  float4 a3 = ((const float4*)xr1)[1];
  {
    u16* As = SMEM[0];
    u16* Bs = SMEM[0] + 4096;
    for (int j = 0; j < 4; ++j) {
      int e8 = (j * 256 + tid) * 8;
      int rr = e8 >> 6, kk = e8 & 63;
      gload16(Wp + (size_t)rr * C_DIM + kk, &Bs[e8]);
    }
    u16x8 pk;
    pk[0] = f2bf(a0.x); pk[1] = f2bf(a0.y); pk[2] = f2bf(a0.z); pk[3] = f2bf(a0.w);
    pk[4] = f2bf(a1.x); pk[5] = f2bf(a1.y); pk[6] = f2bf(a1.z); pk[7] = f2bf(a1.w);
    *(u16x8*)&As[arow * 64 + aswz] = pk;
    pk[0] = f2bf(a2.x); pk[1] = f2bf(a2.y); pk[2] = f2bf(a2.z); pk[3] = f2bf(a2.w);
    pk[4] = f2bf(a3.x); pk[5] = f2bf(a3.y); pk[6] = f2bf(a3.z); pk[7] = f2bf(a3.w);
    *(u16x8*)&As[(arow + 32) * 64 + aswz] = pk;
  }
  a0 = ((const float4*)(xr0 + 64))[0];
  a1 = ((const float4*)(xr0 + 64))[1];
  a2 = ((const float4*)(xr1 + 64))[0];
  a3 = ((const float4*)(xr1 + 64))[1];

  for (int it = 0; it < 32; ++it) {
    const int cur = it & 1, nxt = cur ^ 1;
    __syncthreads();   // staging of buf[cur] (issued one iter ago) drains

    if (it + 1 < 32) {
      const int k1 = (it + 1) * 64;
      u16* As = SMEM[nxt];
      u16* Bs = SMEM[nxt] + 4096;
      for (int j = 0; j < 4; ++j) {
        int e8 = (j * 256 + tid) * 8;
        int rr = e8 >> 6, kk = e8 & 63;
        gload16(Wp + (size_t)rr * C_DIM + k1 + kk, &Bs[e8]);
      }
      u16x8 pk;
      pk[0] = f2bf(a0.x); pk[1] = f2bf(a0.y); pk[2] = f2bf(a0.z); pk[3] = f2bf(a0.w);
      pk[4] = f2bf(a1.x); pk[5] = f2bf(a1.y); pk[6] = f2bf(a1.z); pk[7] = f2bf(a1.w);
      *(u16x8*)&As[arow * 64 + aswz] = pk;
      pk[0] = f2bf(a2.x); pk[1] = f2bf(a2.y); pk[2] = f2bf(a2.z); pk[3] = f2bf(a2.w);
      pk[4] = f2bf(a3.x); pk[5] = f2bf(a3.y); pk[6] = f2bf(a3.z); pk[7] = f2bf(a3.w);
      *(u16x8*)&As[(arow + 32) * 64 + aswz] = pk;
      if (it + 2 < 32) {
        const float4* xp0 = (const float4*)(xr0 + (it + 2) * 64);
        const float4* xp1 = (const float4*)(xr1 + (it + 2) * 64);
        a0 = xp0[0]; a1 = xp0[1]; a2 = xp1[0]; a3 = xp1[1];
      }
    }

    u16* As = SMEM[cur];
    u16* Bs = SMEM[cur] + 4096;
    for (int ks = 0; ks < 2; ++ks) {
      bf16x8 af[2], bfr[4];
      const int ksz = (((ks * 4 + quad) ^ (t16 & 7)) << 3);
      for (int ra = 0; ra < 2; ++ra)
        af[ra] = *(const bf16x8*)&As[(mh * 32 + ra * 16 + t16) * 64 + ksz];
      for (int c = 0; c < 4; ++c) {
        int col = nq * 64 + c * 16 + t16;
        bfr[c] = *(const bf16x8*)&Bs[col * 64 + ksz];
      }
      for (int ra = 0; ra < 2; ++ra)
        for (int c = 0; c < 4; ++c)
          acc[ra][c] = mfma_bf16(af[ra], bfr[c], acc[ra][c]);
    }
  }

  // ---- epilogue: acc -> LDS in exact global layout for this p ----
  __syncthreads();
  u16* O = SMEM[0];   // 16 KB tile

  const float QSCALE = 0.022097086912079612f;   // 2048^-0.5 folded into q
  for (int c = 0; c < 4; ++c) {
    int pc = nq * 64 + c * 16 + t16;   // 0..127
    float bias = bias_p[pc];
    for (int ra = 0; ra < 2; ++ra) {
      for (int r = 0; r < 4; ++r) {
        int row16 = mh * 32 + ra * 16 + quad * 4 + r;   // 0..63
        float v = acc[ra][c][r] + bias;
        if (p == 0) v *= QSCALE;
        if (p == 2) {
          int gt = row16 >> 3;
          O[pc * 64 + ((gt ^ (pc & 7)) << 3) + (row16 & 7)] = f2bf(v);
        } else {
          int g = pc >> 3;
          O[row16 * 128 + (((g ^ (row16 & 15)) << 3) | (pc & 7))] = f2bf(v);
        }
      }
    }
  }
  __syncthreads();

  // coalesced 16B stores (1024 chunks, 4 per thread)
  const int bb = rt >> 6;            // batch
  const int tb = (rt & 63) * 64;     // t offset within batch
  for (int j = 0; j < 4; ++j) {
    int c = j * 256 + tid;
    if (p == 0) {
      int row16 = c >> 4, g = c & 15;
      u16x8 v = *(const u16x8*)&O[row16 * 128 + ((g ^ (row16 & 15)) << 3)];
      *(u16x8*)&qo[(rowBase + row16) * H_DIM + g * 8] = v;
    } else if (p == 1) {
      *(u16x8*)&ko[rowBase * H_DIM + c * 8] = *(const u16x8*)&O[c * 8];
    } else {
      int d = c >> 3, gc = c & 7;
      *(u16x8*)&vTo[((size_t)bb * H_DIM + d) * T_SEQ + tb + gc * 8] =
          *(const u16x8*)&O[c * 8];
    }
  }
}

// ---------------------------------------------------------------------------
// Kernel 3: causal flash attention — HYBRID operand paths (byte-identical to
// the measured R11 kernel, 297.6us total, flash ~50us inferred). K stays
// LDS-prefetched; V direct from global issued right after QK^T.
// ---------------------------------------------------------------------------
__global__ __launch_bounds__(256, 3) void flash_attn(
    const u16* __restrict__ q, const u16* __restrict__ k,
    const u16* __restrict__ vT, float* __restrict__ out,
    void* __restrict__ OpartRaw, float* __restrict__ MLpart,
    int split, int pf32)
{
  __shared__ alignas(16) u16 Kt[2][64 * 128];    // 2 x 16 KB
  __shared__ alignas(16) u16 Ps[4 * 16 * 72];    // 9 KB

  const int tid  = threadIdx.x;
  const int w    = tid >> 6, lane = tid & 63;
  const int t16  = lane & 15, quad = lane >> 4;
  const int b    = blockIdx.x;

  // ---- schedule: (qt, chunk) from blockIdx.y (Round-7, HW-verified) ----
  int qt, kt0, ktn, mls, esd;   // mls<0 => direct; esd==-2 => chunk0 -> out
  if (split) {
    const int j = blockIdx.y;   // 0..159
    int c, n;
    if (j < 64)       { qt = 63 - (j >> 2); c = j & 3; n = 4; }
    else if (j < 112) { int t = j - 64; int d3 = t / 3; qt = 47 - d3; c = t - d3 * 3; n = 3; }
    else if (j < 144) { int t = j - 112; qt = 31 - (t >> 1); c = t & 1; n = 2; }
    else              { qt = 159 - j; c = 0; n = 1; }
    const int NT = qt + 1;
    kt0 = c * NT / n;
    ktn = (c + 1) * NT / n - kt0;
    if (n == 1) { mls = -1; esd = -1; }
    else {
      int mlb, esb;
      if (qt >= 48)      { mlb = (qt - 48) * 4;       esb = (qt - 48) * 3; }
      else if (qt >= 32) { mlb = 64 + (qt - 32) * 3;  esb = 48 + (qt - 32) * 2; }
      else               { mlb = 112 + (qt - 16) * 2; esb = 80 + (qt - 16); }
      mls = b * 144 + mlb + c;
      esd = (c >= 1) ? (b * 96 + esb + c - 1) : -2;
    }
  } else {
    qt = 63 - blockIdx.y; kt0 = 0; ktn = qt + 1; mls = -1; esd = -1;
  }

  const float L2E = 1.4426950408889634f;

  bf16x8 qf[4];
  {
    const u16* qrow = q + ((size_t)(b * T_SEQ + qt * 64 + w * 16 + t16)) * H_DIM;
    for (int c = 0; c < 4; ++c)
      qf[c] = *(const bf16x8*)(qrow + c * 32 + quad * 8);
  }

  f32x4 Oc[8];
  for (int i = 0; i < 8; ++i) Oc[i] = f32x4{0.f, 0.f, 0.f, 0.f};
  float mrow[4] = {-1e30f, -1e30f, -1e30f, -1e30f};
  float lrow[4] = {0.f, 0.f, 0.f, 0.f};

  const u16* kbase = k  + ((size_t)b * T_SEQ) * H_DIM;
  const u16* vbase = vT + ((size_t)b * H_DIM) * T_SEQ;

  // prefetch first K tile into buffer 0 (4 gload16 per thread = 16 KB)
  {
    const u16* kg = kbase + (size_t)(kt0 * 64) * H_DIM;
    for (int j = 0; j < 4; ++j) {
      int e8 = (((j << 2) + w) * 64 + lane) * 8;
      gload16(kg + e8, &Kt[0][e8]);
    }
  }

  int cur = 0;
  for (int it = 0; it < ktn; ++it) {
    const int kt = kt0 + it;
    __syncthreads();   // drains prefetch of `cur`; WAR-guard for next prefetch
    if (it + 1 < ktn) {
      const int nb = cur ^ 1;
      const u16* kg = kbase + (size_t)((kt + 1) * 64) * H_DIM;
      for (int j = 0; j < 4; ++j) {
        int e8 = (((j << 2) + w) * 64 + lane) * 8;
        gload16(kg + e8, &Kt[nb][e8]);
      }
    }

    // S = Q K^T  (K from LDS, prefetched; logits pre-scaled via q)
    f32x4 S[4];
    for (int ct = 0; ct < 4; ++ct) S[ct] = f32x4{0.f, 0.f, 0.f, 0.f};
    __builtin_amdgcn_s_setprio(1);
    for (int c = 0; c < 4; ++c) {
      for (int ct = 0; ct < 4; ++ct) {
        bf16x8 kf = *(const bf16x8*)&Kt[cur][(ct * 16 + t16) * H_DIM +
                                            (((c * 4 + quad) ^ t16) << 3)];
        S[ct] = mfma_bf16(qf[c], kf, S[ct]);
      }
    }
    __builtin_amdgcn_s_setprio(0);

    // V loads issued NOW (direct from global, R10-verified offsets);
    // softmax + P-write below covers their latency before PV consumes them.
    const u16* vg = vbase + kt * 64;
    bf16x8 vf[2][8];
    for (int ks = 0; ks < 2; ++ks)
      for (int dt = 0; dt < 8; ++dt)
        vf[ks][dt] = *(const bf16x8*)&vg[(size_t)(dt * 16 + t16) * T_SEQ +
                                         (((ks * 4 + quad) ^ (t16 & 7)) << 3)];

    if (kt == qt) {   // diagonal tile: causal mask
      for (int ct = 0; ct < 4; ++ct)
        for (int r = 0; r < 4; ++r)
          if (ct * 16 + t16 > w * 16 + quad * 4 + r) S[ct][r] = -1e30f;
    }

    // defer-max online softmax (T13, THR=8 nat-log)
    float alpha[4];
    bool any = false;
    for (int r = 0; r < 4; ++r) {
      float mx = red16_max(fmaxf(fmaxf(S[0][r], S[1][r]), fmaxf(S[2][r], S[3][r])));
      if (mx > mrow[r] + 8.0f) {
        alpha[r] = exp2f((mrow[r] - mx) * L2E);
        mrow[r] = mx;
        any = true;
      } else {
        alpha[r] = 1.0f;
      }
    }
    if (any) {
      for (int r = 0; r < 4; ++r) lrow[r] *= alpha[r];
      for (int dt = 0; dt < 8; ++dt)
        for (int r = 0; r < 4; ++r)
          Oc[dt][r] *= alpha[r];
    }
    for (int r = 0; r < 4; ++r) {
      float s = 0.f;
      for (int ct = 0; ct < 4; ++ct) {
        float pv = exp2f((S[ct][r] - mrow[r]) * L2E);
        S[ct][r] = pv;
        s += pv;
      }
      lrow[r] += red16_sum(s);
    }

    // P: C layout -> A layout via padded per-wave LDS scratch
    u16* pw = &Ps[w * 1152];
    for (int ct = 0; ct < 4; ++ct)
      for (int r = 0; r < 4; ++r)
        pw[(quad * 4 + r) * 72 + ct * 16 + t16] = f2bf(S[ct][r]);
    __asm__ volatile("s_waitcnt lgkmcnt(0)" ::: "memory");

    __builtin_amdgcn_s_setprio(1);
    for (int ks = 0; ks < 2; ++ks) {
      bf16x8 pf = *(const bf16x8*)&pw[t16 * 72 + ks * 32 + quad * 8];
      for (int dt = 0; dt < 8; ++dt)
        Oc[dt] = mfma_bf16(pf, vf[ks][dt], Oc[dt]);
    }
    __builtin_amdgcn_s_setprio(0);
    cur ^= 1;
  }

  if (mls < 0) {
    for (int r = 0; r < 4; ++r) {
      float inv = 1.0f / lrow[r];
      size_t row = (size_t)b * T_SEQ + qt * 64 + w * 16 + quad * 4 + r;
      for (int dt = 0; dt < 8; ++dt)
        out[row * H_DIM + dt * 16 + t16] = Oc[dt][r] * inv;
    }
  } else {
    if (t16 == 0)
      for (int r = 0; r < 4; ++r) {
        int row = w * 16 + quad * 4 + r;
        MLpart[(size_t)mls * 128 + row * 2 + 0] = mrow[r];
        MLpart[(size_t)mls * 128 + row * 2 + 1] = lrow[r];
      }
    if (esd == -2) {
      // chunk 0: unnormalized partial straight into out (combine rescales)
      for (int r = 0; r < 4; ++r) {
        size_t row = (size_t)b * T_SEQ + qt * 64 + w * 16 + quad * 4 + r;
        for (int dt = 0; dt < 8; ++dt)
          out[row * H_DIM + dt * 16 + t16] = Oc[dt][r];
      }
    } else if (pf32) {
      float* op = (float*)OpartRaw + (size_t)esd * 8192;
      for (int r = 0; r < 4; ++r) {
        int row = w * 16 + quad * 4 + r;
        for (int dt = 0; dt < 8; ++dt)
          op[row * 128 + dt * 16 + t16] = Oc[dt][r];
      }
    } else {
      u16* op = (u16*)OpartRaw + (size_t)esd * 8192;
      for (int r = 0; r < 4; ++r) {
        int row = w * 16 + quad * 4 + r;
        for (int dt = 0; dt < 8; ++dt)
          op[row * 128 + dt * 16 + t16] = f2bf(Oc[dt][r]);
      }
    }
  }
}

// ---------------------------------------------------------------------------
// Kernel 4: merge chunk 0 (in out, unnormalized fp32) with chunks 1..n-1
// (Opart, fp32 or bf16). One block per split (b,qt); n in {2,3,4}.
// (Round-7 version, HW-verified.)
// ---------------------------------------------------------------------------
__global__ __launch_bounds__(256) void combine(
    const void* __restrict__ OpartRaw, const float* __restrict__ MLpart,
    float* __restrict__ out, int pf32)
{
  __shared__ float cs[4][64];
  const float L2E = 1.4426950408889634f;
  const int s = blockIdx.x;            // 0..191
  const int b = s / 48, qt = 16 + (s % 48);
  const int t = threadIdx.x;

  int n, mlb, esb;
  if (qt >= 48)      { n = 4; mlb = (qt - 48) * 4;       esb = (qt - 48) * 3; }
  else if (qt >= 32) { n = 3; mlb = 64 + (qt - 32) * 3;  esb = 48 + (qt - 32) * 2; }
  else               { n = 2; mlb = 112 + (qt - 16) * 2; esb = 80 + (qt - 16); }
  const int mls0 = b * 144 + mlb;
  const int esd0 = b * 96 + esb;

  if (t < 64) {
    float m[4], l[4];
    float mg = -1e30f;
    for (int c = 0; c < n; ++c) {
      const float* ML = MLpart + (size_t)(mls0 + c) * 128;
      m[c] = ML[t * 2]; l[c] = ML[t * 2 + 1];
      mg = fmaxf(mg, m[c]);
    }
    float denom = 0.f, e[4];
    for (int c = 0; c < n; ++c) {
      e[c] = exp2f((m[c] - mg) * L2E);
      denom += l[c] * e[c];
    }
    float inv = 1.0f / denom;
    for (int c = 0; c < n; ++c) cs[c][t] = e[c] * inv;
  }
  __syncthreads();

  float* o = out + ((size_t)b * T_SEQ + (size_t)qt * 64) * (size_t)H_DIM;
  for (int i4 = t; i4 < 2048; i4 += 256) {       // float4 chunks, 32 per row
    const int row = i4 >> 5;
    float4 acc = ((float4*)o)[i4];
    const float c0 = cs[0][row];
    acc.x *= c0; acc.y *= c0; acc.z *= c0; acc.w *= c0;
    for (int c = 1; c < n; ++c) {
      const float cc = cs[c][row];
      if (pf32) {
        const float4 p = ((const float4*)((const float*)OpartRaw +
                          (size_t)(esd0 + c - 1) * 8192))[i4];
        acc.x += p.x * cc; acc.y += p.y * cc;
        acc.z += p.z * cc; acc.w += p.w * cc;
      } else {
        const u16x4 p = ((const u16x4*)((const u16*)OpartRaw +
                         (size_t)(esd0 + c - 1) * 8192))[i4];
        acc.x += bf2f(p[0]) * cc; acc.y += bf2f(p[1]) * cc;
        acc.z += bf2f(p[2]) * cc; acc.w += bf2f(p[3]) * cc;
      }
    }
    ((float4*)o)[i4] = acc;
  }
}

// ---------------------------------------------------------------------------
extern "C" void kernel_launch(void* const* d_in, const int* in_sizes, int n_in,
                              void* d_out, int out_size, void* d_ws, size_t ws_size,
                              hipStream_t stream) {
  const float* x  = (const float*)d_in[0];
  const float* Wk = (const float*)d_in[1];
  const float* bk = (const float*)d_in[2];
  const float* Wq = (const float*)d_in[3];
  const float* bq = (const float*)d_in[4];
  const float* Wv = (const float*)d_in[5];
  const float* bv = (const float*)d_in[6];
  float* out = (float*)d_out;

  char* ws = (char*)d_ws;
  u16* qb  = (u16*)(ws);                       // 4 MB  [b][t][128] bf16 (pre-scaled)
  u16* kb  = (u16*)(ws + 4194304);             // 4 MB  [b][t][d'] bf16 (swizzled)
  u16* vT  = (u16*)(ws + 8388608);             // 4 MB  [b][128][t'] bf16 (swizzled)
  u16* Wt  = (u16*)(ws + 12582912);            // 1.5 MB pre-swizzled weights
  void* Opart = (void*)(ws + 14155776);        // partials: 384 slots of 64x128

  const size_t base     = 14155776ull;
  const size_t ml_bytes = 294912ull;           // 576 slots x 128 f32
  const size_t need_f32 = base + 12582912ull + ml_bytes;   // fp32 partials
  const size_t need_b16 = base + 6291456ull  + ml_bytes;   // bf16 partials

  int split, pf32;
  float* MLpart;
  if (ws_size >= need_f32) {
    split = 1; pf32 = 1;
    MLpart = (float*)(ws + base + 12582912ull);
  } else if (ws_size >= need_b16) {
    split = 1; pf32 = 0;
    MLpart = (float*)(ws + base + 6291456ull);
  } else {
    split = 0; pf32 = 0;
    MLpart = (float*)(ws + base);              // unused
  }

  hipLaunchKernelGGL(transpose_w, dim3(32, 2, 3), dim3(256), 0, stream, Wq, Wk, Wv, Wt);
  hipLaunchKernelGGL(qkv_fused, dim3(256, 3), dim3(256), 0, stream,
                     x, Wt, bq, bk, bv, qb, kb, vT);
  hipLaunchKernelGGL(flash_attn, dim3(4, split ? 160 : 64), dim3(256), 0, stream,
                     qb, kb, vT, out, Opart, MLpart, split, pf32);
  if (split)
    hipLaunchKernelGGL(combine, dim3(192), dim3(256), 0, stream, Opart, MLpart, out, pf32);
}